// Round 14
// baseline (331.359 us; speedup 1.0000x reference)
//
#include <hip/hip_runtime.h>
#include <cstdint>
#include <cstddef>

// B=2 S=1024 H=4096 NH=32 NKV=8 HD=128 GROUPS=4
typedef short bf16x8 __attribute__((ext_vector_type(8)));
typedef float f32x4 __attribute__((ext_vector_type(4)));

__device__ __forceinline__ unsigned short f2bf(float f) {
  unsigned int u = __builtin_bit_cast(unsigned int, f);
  u += 0x7fffu + ((u >> 16) & 1u);
  return (unsigned short)(u >> 16);
}

// ---- transpose tile helper: 64x64, float4 loads / bf16x8 stores ----
__device__ __forceinline__ void transpose_tile(const float* __restrict__ src,
                                               unsigned short* __restrict__ dst,
                                               int K, int N, int n0, int k0, int tid) {
  __shared__ float t[64][65];
  const int lr = tid >> 4, lc = (tid & 15) * 4;
#pragma unroll
  for (int i = 0; i < 4; ++i) {
    float4 v = *(const float4*)(src + (size_t)(k0 + i * 16 + lr) * N + n0 + lc);
    t[i * 16 + lr][lc] = v.x;
    t[i * 16 + lr][lc + 1] = v.y;
    t[i * 16 + lr][lc + 2] = v.z;
    t[i * 16 + lr][lc + 3] = v.w;
  }
  __syncthreads();
  const int nr = tid >> 3, kk = (tid & 7) * 8;
#pragma unroll
  for (int i = 0; i < 2; ++i) {
    int n = nr + i * 32;
    bf16x8 v;
#pragma unroll
    for (int j = 0; j < 8; ++j) v[j] = (short)f2bf(t[kk + j][n]);
    *(bf16x8*)(dst + (size_t)(n0 + n) * K + k0 + kk) = v;
  }
}

// ---- fused prep: x convert (blocks [0,8192)), w_qkv transpose [8192,14336),
// w_o transpose [14336,18432). Whole blocks take one path (no divergence). ----
__global__ __launch_bounds__(256) void k_prep(const float* __restrict__ x,
                                              const float* __restrict__ w_qkv,
                                              const float* __restrict__ w_o,
                                              unsigned short* __restrict__ xb,
                                              unsigned short* __restrict__ wqkv_t,
                                              unsigned short* __restrict__ wo_t) {
  const int bid = blockIdx.x, tid = threadIdx.x;
  if (bid < 8192) {
    int i = bid * 256 + tid;
    float4 v = ((const float4*)x)[i];
    ushort4 o;
    o.x = f2bf(v.x); o.y = f2bf(v.y); o.z = f2bf(v.z); o.w = f2bf(v.w);
    ((ushort4*)xb)[i] = o;
  } else if (bid < 14336) {
    int t = bid - 8192;
    transpose_tile(w_qkv, wqkv_t, 4096, 6144, (t % 96) * 64, (t / 96) * 64, tid);
  } else {
    int t = bid - 14336;
    transpose_tile(w_o, wo_t, 4096, 4096, (t & 63) * 64, (t >> 6) * 64, tid);
  }
}

// ---- GEMM: A[M,K]bf16 @ Bt[N,K]bf16^T ; BM=BN=128, BK=64, 4 waves.
// 2-barrier/K-step skeleton + DEPTH-2 register prefetch (two NAMED reg sets,
// load(k+2) issued after tile-k's write barrier -> ~2.5 phases of load slack).
// Single 32KB LDS. NO min-waves bound (R12: (256,4) capped regs at 128 and
// spilled staging to scratch -> 1.4GB scratch traffic; occupancy here is
// grid-limited at 3 blocks/CU, so VGPR<=170 costs nothing). T1 XCD swizzle.
// MODE 0: C[M,N] f32.  MODE 1: fused RoPE + Q/K/V scatter epilogue (qkv proj).
template <int MODE>
__global__ __launch_bounds__(256) void k_gemm(const unsigned short* __restrict__ A,
                                              const unsigned short* __restrict__ Bt,
                                              float* __restrict__ C,
                                              unsigned short* __restrict__ Qr,
                                              unsigned short* __restrict__ Kr,
                                              unsigned short* __restrict__ Vt,
                                              const float* __restrict__ cosT,
                                              const float* __restrict__ sinT,
                                              int M, int N, int K) {
  __shared__ __align__(16) unsigned short lA[128 * 64];
  __shared__ __align__(16) unsigned short lB[128 * 64];
  const int tid = threadIdx.x;
  const int lane = tid & 63, wv = tid >> 6;
  const int wr = wv >> 1, wc = wv & 1;
  const int lid = blockIdx.y * gridDim.x + blockIdx.x;
  const int cpx = (gridDim.x * gridDim.y) >> 3;
  const int swz = (lid & 7) * cpx + (lid >> 3);
  const int bm = (swz % gridDim.x) * 128, bn = (swz / gridDim.x) * 128;
  const int l16 = lane & 15, lhi = lane >> 4;
  f32x4 acc[4][4] = {};
  bf16x8 a0[4], b0[4], a1[4], b1[4];

  auto loadT = [&](int kofs, bf16x8 (&ar)[4], bf16x8 (&br)[4]) {
#pragma unroll
    for (int i = 0; i < 4; ++i) {
      int c = tid + i * 256, row = c >> 3, c16 = c & 7;
      ar[i] = *(const bf16x8*)(A + (size_t)(bm + row) * K + kofs + c16 * 8);
      br[i] = *(const bf16x8*)(Bt + (size_t)(bn + row) * K + kofs + c16 * 8);
    }
  };
  auto writeT = [&](bf16x8 (&ar)[4], bf16x8 (&br)[4]) {
#pragma unroll
    for (int i = 0; i < 4; ++i) {
      int c = tid + i * 256, row = c >> 3, c16 = c & 7;
      int pc = c16 ^ (row & 7);
      *(bf16x8*)((char*)lA + row * 128 + pc * 16) = ar[i];
      *(bf16x8*)((char*)lB + row * 128 + pc * 16) = br[i];
    }
  };
  auto computeT = [&]() {
#pragma unroll
    for (int s = 0; s < 2; ++s) {
      bf16x8 af[4], bfr[4];
#pragma unroll
      for (int f = 0; f < 4; ++f) {
        int rowa = wr * 64 + f * 16 + l16;
        int ca = (s * 4 + lhi) ^ (rowa & 7);
        af[f] = *(const bf16x8*)((char*)lA + rowa * 128 + ca * 16);
        int rowb = wc * 64 + f * 16 + l16;
        int cb = (s * 4 + lhi) ^ (rowb & 7);
        bfr[f] = *(const bf16x8*)((char*)lB + rowb * 128 + cb * 16);
      }
#pragma unroll
      for (int fi = 0; fi < 4; ++fi)
#pragma unroll
        for (int fj = 0; fj < 4; ++fj)
          acc[fi][fj] = __builtin_amdgcn_mfma_f32_16x16x32_bf16(af[fi], bfr[fj], acc[fi][fj], 0, 0, 0);
    }
  };

  loadT(0, a0, b0);
  loadT(64, a1, b1);
  const int nkt = K >> 6; // 64: even
  for (int kt = 0; kt < nkt; kt += 2) {
    __syncthreads();            // WAR: reads of prev tile done
    writeT(a0, b0);
    __syncthreads();            // writes visible
    if (kt + 2 < nkt) loadT((kt + 2) << 6, a0, b0);
    computeT();
    __syncthreads();
    writeT(a1, b1);
    __syncthreads();
    if (kt + 3 < nkt) loadT((kt + 3) << 6, a1, b1);
    computeT();
  }

  if (MODE == 0) {
#pragma unroll
    for (int fi = 0; fi < 4; ++fi) {
      int rbase = bm + wr * 64 + fi * 16 + lhi * 4;
#pragma unroll
      for (int fj = 0; fj < 4; ++fj) {
        int col = bn + wc * 64 + fj * 16 + l16;
#pragma unroll
        for (int r = 0; r < 4; ++r)
          C[(size_t)(rbase + r) * N + col] = acc[fi][fj][r];
      }
    }
  } else {
    // qkv: cols [0,4096)=Q rope, [4096,5120)=K rope, [5120,6144)=V transpose.
#pragma unroll
    for (int fi = 0; fi < 4; ++fi) {
      int rbase = bm + wr * 64 + fi * 16 + lhi * 4;
      int b = rbase >> 10, sbase = rbase & 1023;
#pragma unroll
      for (int fj = 0; fj < 4; ++fj) {
        int col = bn + wc * 64 + fj * 16 + l16;
        if (col < 5120) {
          int i = (col & 127) >> 1;
          float sgn = (col & 1) ? 1.0f : -1.0f;
          unsigned short* dst;
          if (col < 4096)
            dst = Qr + ((size_t)(b * 32 + (col >> 7)) * 1024) * 128 + (col & 127);
          else
            dst = Kr + ((size_t)(b * 8 + ((col - 4096) >> 7)) * 1024) * 128 + (col & 127);
#pragma unroll
          for (int r = 0; r < 4; ++r) {
            float own = acc[fi][fj][r];
            float other = __shfl_xor(own, 1);
            int s = sbase + r;
            float c = cosT[s * 64 + i], sn = sinT[s * 64 + i];
            dst[(size_t)s * 128] = f2bf(own * c + sgn * other * sn);
          }
        } else {
          int kvh = (col - 5120) >> 7, d = col & 127;
          unsigned short* dst = Vt + ((size_t)(b * 8 + kvh) * 128 + d) * 1024;
#pragma unroll
          for (int r = 0; r < 4; ++r) dst[sbase + r] = f2bf(acc[fi][fj][r]);
        }
      }
    }
  }
}

// ---- flash attention: QBLK=64, LPT dispatch, T13 defer-max, T14 prefetch,
// XOR-swizzled K/V LDS (R13 proven) ----
__global__ __launch_bounds__(256) void k_attn(const unsigned short* __restrict__ Qr,
                                              const unsigned short* __restrict__ Kr,
                                              const unsigned short* __restrict__ Vt,
                                              unsigned short* __restrict__ Out) {
  __shared__ __align__(16) unsigned short lK[64 * 128];
  __shared__ __align__(16) unsigned short lV[128 * 64];
  __shared__ __align__(16) unsigned short lP[4 * 16 * 64];
  const int tid = threadIdx.x, lane = tid & 63, wv = tid >> 6;
  const int qt = (int)gridDim.x - 1 - (int)blockIdx.x; // LPT: heavy blocks first
  const int h = blockIdx.y, b = blockIdx.z;
  const int kvh = h >> 2;
  const int q0 = qt * 64;
  const int l16 = lane & 15, lhi = lane >> 4;

  const unsigned short* Qbase = Qr + ((size_t)(b * 32 + h) * 1024 + q0 + wv * 16 + l16) * 128;
  bf16x8 qf[4];
#pragma unroll
  for (int s = 0; s < 4; ++s) qf[s] = *(const bf16x8*)(Qbase + s * 32 + lhi * 8);

  const unsigned short* Kbase = Kr + (size_t)(b * 8 + kvh) * 1024 * 128;
  const unsigned short* Vbase = Vt + (size_t)(b * 8 + kvh) * 128 * 1024;

  f32x4 oacc[8] = {};
  float mrow[4] = {-1e30f, -1e30f, -1e30f, -1e30f};
  float lrow[4] = {0.f, 0.f, 0.f, 0.f};
  const int ntk = qt + 1;
  bf16x8 kreg[4], vreg[4];

#pragma unroll
  for (int i = 0; i < 4; ++i) {
    int c = tid + i * 256;
    int krow = c >> 4, kc = c & 15;
    kreg[i] = *(const bf16x8*)(Kbase + (size_t)krow * 128 + kc * 8);
    int vrow = c >> 3, vc = c & 7;
    vreg[i] = *(const bf16x8*)(Vbase + (size_t)vrow * 1024 + vc * 8);
  }

  for (int kt = 0; kt < ntk; ++kt) {
    const int k0 = kt * 64;
    __syncthreads();
#pragma unroll
    for (int i = 0; i < 4; ++i) {
      int c = tid + i * 256;
      int krow = c >> 4, kc = c & 15;
      *(bf16x8*)((char*)lK + krow * 256 + (kc ^ (krow & 7)) * 16) = kreg[i];
      int vrow = c >> 3, vc = c & 7;
      *(bf16x8*)((char*)lV + vrow * 128 + (vc ^ (vrow & 7)) * 16) = vreg[i];
    }
    __syncthreads();

    if (kt + 1 < ntk) {
      const int kn = (kt + 1) * 64;
#pragma unroll
      for (int i = 0; i < 4; ++i) {
        int c = tid + i * 256;
        int krow = c >> 4, kc = c & 15;
        kreg[i] = *(const bf16x8*)(Kbase + (size_t)(kn + krow) * 128 + kc * 8);
        int vrow = c >> 3, vc = c & 7;
        vreg[i] = *(const bf16x8*)(Vbase + (size_t)vrow * 1024 + kn + vc * 8);
      }
    }

    f32x4 sacc[4] = {};
#pragma unroll
    for (int kf = 0; kf < 4; ++kf) {
      int rowk = kf * 16 + l16;
#pragma unroll
      for (int s = 0; s < 4; ++s) {
        int ck = (s * 4 + lhi) ^ (rowk & 7);
        bf16x8 kfr = *(const bf16x8*)((char*)lK + rowk * 256 + ck * 16);
        sacc[kf] = __builtin_amdgcn_mfma_f32_16x16x32_bf16(qf[s], kfr, sacc[kf], 0, 0, 0);
      }
    }

    const int qg = q0 + wv * 16 + lhi * 4;
    float mt[4] = {-1e30f, -1e30f, -1e30f, -1e30f};
#pragma unroll
    for (int kf = 0; kf < 4; ++kf) {
      int kg = k0 + kf * 16 + l16;
#pragma unroll
      for (int r = 0; r < 4; ++r) {
        float v = sacc[kf][r] * 0.08838834764831845f;
        v = (kg <= qg + r) ? v : -1e9f;
        sacc[kf][r] = v;
        mt[r] = fmaxf(mt[r], v);
      }
    }
#pragma unroll
    for (int r = 0; r < 4; ++r) {
#pragma unroll
      for (int off = 1; off < 16; off <<= 1) mt[r] = fmaxf(mt[r], __shfl_xor(mt[r], off));
    }

    // T13 defer-max: skip rescale (keep old mrow) unless some row grew > 8.
    bool need = false;
#pragma unroll
    for (int r = 0; r < 4; ++r) need = need || (mt[r] > mrow[r] + 8.0f);
    const bool doresc = (__ballot(need) != 0ull); // wave-uniform

    float alpha[4], rs[4];
#pragma unroll
    for (int r = 0; r < 4; ++r) {
      if (doresc) {
        float mn = fmaxf(mrow[r], mt[r]);
        alpha[r] = __expf(mrow[r] - mn);
        mrow[r] = mn;
      } else {
        alpha[r] = 1.0f;
      }
      rs[r] = 0.f;
    }
#pragma unroll
    for (int kf = 0; kf < 4; ++kf) {
      int key = kf * 16 + l16;
#pragma unroll
      for (int r = 0; r < 4; ++r) {
        float p = __expf(sacc[kf][r] - mrow[r]); // <= e^8 when deferred
        rs[r] += p;
        int prow = lhi * 4 + r;
        int addr = wv * 2048 + ((prow * 128 + key * 2) ^ ((prow & 7) << 4));
        *(unsigned short*)((char*)lP + addr) = f2bf(p);
      }
    }
#pragma unroll
    for (int r = 0; r < 4; ++r) {
#pragma unroll
      for (int off = 1; off < 16; off <<= 1) rs[r] += __shfl_xor(rs[r], off);
      lrow[r] = lrow[r] * alpha[r] + rs[r];
    }
    if (doresc) {
#pragma unroll
      for (int nf = 0; nf < 8; ++nf)
#pragma unroll
        for (int r = 0; r < 4; ++r) oacc[nf][r] *= alpha[r];
    }

#pragma unroll
    for (int s2 = 0; s2 < 2; ++s2) {
      int prow = l16;
      int paddr = wv * 2048 + ((prow * 128 + s2 * 64 + lhi * 16) ^ ((prow & 7) << 4));
      bf16x8 pa = *(const bf16x8*)((char*)lP + paddr);
#pragma unroll
      for (int nf = 0; nf < 8; ++nf) {
        int rowd = nf * 16 + l16;
        int cv = (s2 * 4 + lhi) ^ (rowd & 7);
        bf16x8 vfr = *(const bf16x8*)((char*)lV + rowd * 128 + cv * 16);
        oacc[nf] = __builtin_amdgcn_mfma_f32_16x16x32_bf16(pa, vfr, oacc[nf], 0, 0, 0);
      }
    }
  }

  unsigned short* Ob = Out + ((size_t)(b * 1024) + q0 + wv * 16 + lhi * 4) * 4096 + h * 128;
#pragma unroll
  for (int r = 0; r < 4; ++r) {
    float inv = 1.f / lrow[r];
#pragma unroll
    for (int nf = 0; nf < 8; ++nf)
      Ob[(size_t)r * 4096 + nf * 16 + l16] = f2bf(oacc[nf][r] * inv);
  }
}

extern "C" void kernel_launch(void* const* d_in, const int* in_sizes, int n_in,
                              void* d_out, int out_size, void* d_ws, size_t ws_size,
                              hipStream_t stream) {
  const float* x = (const float*)d_in[0];
  const float* w_qkv = (const float*)d_in[1];
  const float* w_o = (const float*)d_in[2];
  const float* cosT = (const float*)d_in[3];
  const float* sinT = (const float*)d_in[4];

  char* ws = (char*)d_ws;
  unsigned short* wqkv_t = (unsigned short*)(ws);                 // 6144x4096 bf16
  unsigned short* wo_t   = (unsigned short*)(ws + 50331648);      // 4096x4096 bf16
  unsigned short* xb     = (unsigned short*)(ws + 83886080);      // 2048x4096 bf16
  unsigned short* Qr     = (unsigned short*)(ws + 100663296);     // 2*32*1024*128 bf16
  unsigned short* Kr     = (unsigned short*)(ws + 117440512);     // 2*8*1024*128 bf16
  unsigned short* Vt     = (unsigned short*)(ws + 121634816);     // 2*8*128*1024 bf16
  unsigned short* attn   = (unsigned short*)(ws + 125829120);     // 2048x4096 bf16

  k_prep<<<18432, 256, 0, stream>>>(x, w_qkv, w_o, xb, wqkv_t, wo_t);
  k_gemm<1><<<dim3(16, 48), 256, 0, stream>>>(xb, wqkv_t, nullptr, Qr, Kr, Vt, cosT, sinT,
                                              2048, 6144, 4096);
  k_attn<<<dim3(16, 32, 2), 256, 0, stream>>>(Qr, Kr, Vt, attn);
  k_gemm<0><<<dim3(16, 32), 256, 0, stream>>>(attn, wo_t, (float*)d_out, nullptr, nullptr, nullptr,
                                              nullptr, nullptr, 2048, 4096, 4096);
}

// Round 15
// 319.893 us; speedup vs baseline: 1.0358x; 1.0358x over previous
//
#include <hip/hip_runtime.h>
#include <cstdint>
#include <cstddef>

// B=2 S=1024 H=4096 NH=32 NKV=8 HD=128 GROUPS=4
typedef short bf16x8 __attribute__((ext_vector_type(8)));
typedef float f32x4 __attribute__((ext_vector_type(4)));

__device__ __forceinline__ unsigned short f2bf(float f) {
  unsigned int u = __builtin_bit_cast(unsigned int, f);
  u += 0x7fffu + ((u >> 16) & 1u);
  return (unsigned short)(u >> 16);
}

// ---- transpose tile core: 64x64, float4 loads / bf16x8 stores; caller-provided LDS ----
__device__ __forceinline__ void transpose_tile(const float* __restrict__ src,
                                               unsigned short* __restrict__ dst,
                                               int K, int N, int n0, int k0, int tid,
                                               float* __restrict__ tb /* [64][65] */) {
#pragma unroll
  for (int i = 0; i < 4; ++i) {
    const int lr = tid >> 4, lc = (tid & 15) * 4;
    float4 v = *(const float4*)(src + (size_t)(k0 + i * 16 + lr) * N + n0 + lc);
    tb[(i * 16 + lr) * 65 + lc] = v.x;
    tb[(i * 16 + lr) * 65 + lc + 1] = v.y;
    tb[(i * 16 + lr) * 65 + lc + 2] = v.z;
    tb[(i * 16 + lr) * 65 + lc + 3] = v.w;
  }
  __syncthreads();
  const int nr = tid >> 3, kk = (tid & 7) * 8;
#pragma unroll
  for (int i = 0; i < 2; ++i) {
    int n = nr + i * 32;
    bf16x8 v;
#pragma unroll
    for (int j = 0; j < 8; ++j) v[j] = (short)f2bf(tb[(kk + j) * 65 + n]);
    *(bf16x8*)(dst + (size_t)(n0 + n) * K + k0 + kk) = v;
  }
}

// ---- prep: x convert (blocks [0,8192)) + w_qkv transpose [8192,14336) ----
__global__ __launch_bounds__(256) void k_prep(const float* __restrict__ x,
                                              const float* __restrict__ w_qkv,
                                              unsigned short* __restrict__ xb,
                                              unsigned short* __restrict__ wqkv_t) {
  __shared__ float tb[64 * 65];
  const int bid = blockIdx.x, tid = threadIdx.x;
  if (bid < 8192) {
    int i = bid * 256 + tid;
    float4 v = ((const float4*)x)[i];
    ushort4 o;
    o.x = f2bf(v.x); o.y = f2bf(v.y); o.z = f2bf(v.z); o.w = f2bf(v.w);
    ((ushort4*)xb)[i] = o;
  } else {
    int t = bid - 8192;
    transpose_tile(w_qkv, wqkv_t, 4096, 6144, (t % 96) * 64, (t / 96) * 64, tid, tb);
  }
}

// ---- GEMM (R11 proven: depth-1 reg-staged, VGPR 80, 125.8us): BM=BN=128, BK=64,
// 4 waves, XOR-swizzled ds_write, prefetch after barrier, T1 XCD swizzle.
// MODE 0: C[M,N] f32.  MODE 1: fused RoPE + Q/K/V scatter epilogue (qkv proj).
template <int MODE>
__global__ __launch_bounds__(256) void k_gemm(const unsigned short* __restrict__ A,
                                              const unsigned short* __restrict__ Bt,
                                              float* __restrict__ C,
                                              unsigned short* __restrict__ Qr,
                                              unsigned short* __restrict__ Kr,
                                              unsigned short* __restrict__ Vt,
                                              const float* __restrict__ cosT,
                                              const float* __restrict__ sinT,
                                              int M, int N, int K) {
  __shared__ __align__(16) unsigned short lA[128 * 64];
  __shared__ __align__(16) unsigned short lB[128 * 64];
  const int tid = threadIdx.x;
  const int lane = tid & 63, wv = tid >> 6;
  const int wr = wv >> 1, wc = wv & 1;
  const int lid = blockIdx.y * gridDim.x + blockIdx.x;
  const int cpx = (gridDim.x * gridDim.y) >> 3;
  const int swz = (lid & 7) * cpx + (lid >> 3);
  const int bm = (swz % gridDim.x) * 128, bn = (swz / gridDim.x) * 128;
  const int l16 = lane & 15, lhi = lane >> 4;
  f32x4 acc[4][4] = {};
  bf16x8 ar[4], br[4];

#pragma unroll
  for (int i = 0; i < 4; ++i) {
    int c = tid + i * 256, row = c >> 3, c16 = c & 7;
    ar[i] = *(const bf16x8*)(A + (size_t)(bm + row) * K + 0 + c16 * 8);
    br[i] = *(const bf16x8*)(Bt + (size_t)(bn + row) * K + 0 + c16 * 8);
  }
  const int nkt = K >> 6;
  for (int kt = 0; kt < nkt; ++kt) {
    __syncthreads();
#pragma unroll
    for (int i = 0; i < 4; ++i) {
      int c = tid + i * 256, row = c >> 3, c16 = c & 7;
      int pc = c16 ^ (row & 7);
      *(bf16x8*)((char*)lA + row * 128 + pc * 16) = ar[i];
      *(bf16x8*)((char*)lB + row * 128 + pc * 16) = br[i];
    }
    __syncthreads();
    if (kt + 1 < nkt) {
      int kofs = (kt + 1) << 6;
#pragma unroll
      for (int i = 0; i < 4; ++i) {
        int c = tid + i * 256, row = c >> 3, c16 = c & 7;
        ar[i] = *(const bf16x8*)(A + (size_t)(bm + row) * K + kofs + c16 * 8);
        br[i] = *(const bf16x8*)(Bt + (size_t)(bn + row) * K + kofs + c16 * 8);
      }
    }
#pragma unroll
    for (int s = 0; s < 2; ++s) {
      bf16x8 af[4], bfr[4];
#pragma unroll
      for (int f = 0; f < 4; ++f) {
        int rowa = wr * 64 + f * 16 + l16;
        int ca = (s * 4 + lhi) ^ (rowa & 7);
        af[f] = *(const bf16x8*)((char*)lA + rowa * 128 + ca * 16);
        int rowb = wc * 64 + f * 16 + l16;
        int cb = (s * 4 + lhi) ^ (rowb & 7);
        bfr[f] = *(const bf16x8*)((char*)lB + rowb * 128 + cb * 16);
      }
#pragma unroll
      for (int fi = 0; fi < 4; ++fi)
#pragma unroll
        for (int fj = 0; fj < 4; ++fj)
          acc[fi][fj] = __builtin_amdgcn_mfma_f32_16x16x32_bf16(af[fi], bfr[fj], acc[fi][fj], 0, 0, 0);
    }
  }

  if (MODE == 0) {
#pragma unroll
    for (int fi = 0; fi < 4; ++fi) {
      int rbase = bm + wr * 64 + fi * 16 + lhi * 4;
#pragma unroll
      for (int fj = 0; fj < 4; ++fj) {
        int col = bn + wc * 64 + fj * 16 + l16;
#pragma unroll
        for (int r = 0; r < 4; ++r)
          C[(size_t)(rbase + r) * N + col] = acc[fi][fj][r];
      }
    }
  } else {
    // qkv: cols [0,4096)=Q rope, [4096,5120)=K rope, [5120,6144)=V transpose.
#pragma unroll
    for (int fi = 0; fi < 4; ++fi) {
      int rbase = bm + wr * 64 + fi * 16 + lhi * 4;
      int b = rbase >> 10, sbase = rbase & 1023;
#pragma unroll
      for (int fj = 0; fj < 4; ++fj) {
        int col = bn + wc * 64 + fj * 16 + l16;
        if (col < 5120) {
          int i = (col & 127) >> 1;
          float sgn = (col & 1) ? 1.0f : -1.0f;
          unsigned short* dst;
          if (col < 4096)
            dst = Qr + ((size_t)(b * 32 + (col >> 7)) * 1024) * 128 + (col & 127);
          else
            dst = Kr + ((size_t)(b * 8 + ((col - 4096) >> 7)) * 1024) * 128 + (col & 127);
#pragma unroll
          for (int r = 0; r < 4; ++r) {
            float own = acc[fi][fj][r];
            float other = __shfl_xor(own, 1);
            int s = sbase + r;
            float c = cosT[s * 64 + i], sn = sinT[s * 64 + i];
            dst[(size_t)s * 128] = f2bf(own * c + sgn * other * sn);
          }
        } else {
          int kvh = (col - 5120) >> 7, d = col & 127;
          unsigned short* dst = Vt + ((size_t)(b * 8 + kvh) * 128 + d) * 1024;
#pragma unroll
          for (int r = 0; r < 4; ++r) dst[sbase + r] = f2bf(acc[fi][fj][r]);
        }
      }
    }
  }
}

// ---- fused attention + w_o transpose dispatch.
// bid < 1024: attention (QBLK=64, LPT qt order, T13 defer-max, T14 prefetch,
// XOR-swizzled K/V LDS). bid >= 1024: one 64x64 w_o transpose tile — fills
// CUs left idle by attention's causal tail. Shared 40KB LDS union (both
// paths block-uniform -> no divergent barriers).
__global__ __launch_bounds__(256) void k_attn_wo(const unsigned short* __restrict__ Qr,
                                                 const unsigned short* __restrict__ Kr,
                                                 const unsigned short* __restrict__ Vt,
                                                 unsigned short* __restrict__ Out,
                                                 const float* __restrict__ w_o,
                                                 unsigned short* __restrict__ wo_t) {
  __shared__ __align__(16) char smem[40960];
  const int bid = blockIdx.x, tid = threadIdx.x;

  if (bid >= 1024) {
    int t = bid - 1024;
    transpose_tile(w_o, wo_t, 4096, 4096, (t & 63) * 64, (t >> 6) * 64, tid, (float*)smem);
    return;
  }

  unsigned short* lK = (unsigned short*)smem;            // 64*128*2 = 16384
  unsigned short* lV = (unsigned short*)(smem + 16384);  // 128*64*2 = 16384
  unsigned short* lP = (unsigned short*)(smem + 32768);  // 4*16*64*2 = 8192
  const int lane = tid & 63, wv = tid >> 6;
  const int qt = 15 - (bid & 15); // LPT: heavy q-tiles first
  const int h = (bid >> 4) & 31, b = bid >> 9;
  const int kvh = h >> 2;
  const int q0 = qt * 64;
  const int l16 = lane & 15, lhi = lane >> 4;

  const unsigned short* Qbase = Qr + ((size_t)(b * 32 + h) * 1024 + q0 + wv * 16 + l16) * 128;
  bf16x8 qf[4];
#pragma unroll
  for (int s = 0; s < 4; ++s) qf[s] = *(const bf16x8*)(Qbase + s * 32 + lhi * 8);

  const unsigned short* Kbase = Kr + (size_t)(b * 8 + kvh) * 1024 * 128;
  const unsigned short* Vbase = Vt + (size_t)(b * 8 + kvh) * 128 * 1024;

  f32x4 oacc[8] = {};
  float mrow[4] = {-1e30f, -1e30f, -1e30f, -1e30f};
  float lrow[4] = {0.f, 0.f, 0.f, 0.f};
  const int ntk = qt + 1;
  bf16x8 kreg[4], vreg[4];

#pragma unroll
  for (int i = 0; i < 4; ++i) {
    int c = tid + i * 256;
    int krow = c >> 4, kc = c & 15;
    kreg[i] = *(const bf16x8*)(Kbase + (size_t)krow * 128 + kc * 8);
    int vrow = c >> 3, vc = c & 7;
    vreg[i] = *(const bf16x8*)(Vbase + (size_t)vrow * 1024 + vc * 8);
  }

  for (int kt = 0; kt < ntk; ++kt) {
    const int k0 = kt * 64;
    __syncthreads();
#pragma unroll
    for (int i = 0; i < 4; ++i) {
      int c = tid + i * 256;
      int krow = c >> 4, kc = c & 15;
      *(bf16x8*)((char*)lK + krow * 256 + (kc ^ (krow & 7)) * 16) = kreg[i];
      int vrow = c >> 3, vc = c & 7;
      *(bf16x8*)((char*)lV + vrow * 128 + (vc ^ (vrow & 7)) * 16) = vreg[i];
    }
    __syncthreads();

    if (kt + 1 < ntk) {
      const int kn = (kt + 1) * 64;
#pragma unroll
      for (int i = 0; i < 4; ++i) {
        int c = tid + i * 256;
        int krow = c >> 4, kc = c & 15;
        kreg[i] = *(const bf16x8*)(Kbase + (size_t)(kn + krow) * 128 + kc * 8);
        int vrow = c >> 3, vc = c & 7;
        vreg[i] = *(const bf16x8*)(Vbase + (size_t)vrow * 1024 + kn + vc * 8);
      }
    }

    f32x4 sacc[4] = {};
#pragma unroll
    for (int kf = 0; kf < 4; ++kf) {
      int rowk = kf * 16 + l16;
#pragma unroll
      for (int s = 0; s < 4; ++s) {
        int ck = (s * 4 + lhi) ^ (rowk & 7);
        bf16x8 kfr = *(const bf16x8*)((char*)lK + rowk * 256 + ck * 16);
        sacc[kf] = __builtin_amdgcn_mfma_f32_16x16x32_bf16(qf[s], kfr, sacc[kf], 0, 0, 0);
      }
    }

    const int qg = q0 + wv * 16 + lhi * 4;
    float mt[4] = {-1e30f, -1e30f, -1e30f, -1e30f};
#pragma unroll
    for (int kf = 0; kf < 4; ++kf) {
      int kg = k0 + kf * 16 + l16;
#pragma unroll
      for (int r = 0; r < 4; ++r) {
        float v = sacc[kf][r] * 0.08838834764831845f;
        v = (kg <= qg + r) ? v : -1e9f;
        sacc[kf][r] = v;
        mt[r] = fmaxf(mt[r], v);
      }
    }
#pragma unroll
    for (int r = 0; r < 4; ++r) {
#pragma unroll
      for (int off = 1; off < 16; off <<= 1) mt[r] = fmaxf(mt[r], __shfl_xor(mt[r], off));
    }

    bool need = false;
#pragma unroll
    for (int r = 0; r < 4; ++r) need = need || (mt[r] > mrow[r] + 8.0f);
    const bool doresc = (__ballot(need) != 0ull);

    float alpha[4], rs[4];
#pragma unroll
    for (int r = 0; r < 4; ++r) {
      if (doresc) {
        float mn = fmaxf(mrow[r], mt[r]);
        alpha[r] = __expf(mrow[r] - mn);
        mrow[r] = mn;
      } else {
        alpha[r] = 1.0f;
      }
      rs[r] = 0.f;
    }
#pragma unroll
    for (int kf = 0; kf < 4; ++kf) {
      int key = kf * 16 + l16;
#pragma unroll
      for (int r = 0; r < 4; ++r) {
        float p = __expf(sacc[kf][r] - mrow[r]);
        rs[r] += p;
        int prow = lhi * 4 + r;
        int addr = wv * 2048 + ((prow * 128 + key * 2) ^ ((prow & 7) << 4));
        *(unsigned short*)((char*)lP + addr) = f2bf(p);
      }
    }
#pragma unroll
    for (int r = 0; r < 4; ++r) {
#pragma unroll
      for (int off = 1; off < 16; off <<= 1) rs[r] += __shfl_xor(rs[r], off);
      lrow[r] = lrow[r] * alpha[r] + rs[r];
    }
    if (doresc) {
#pragma unroll
      for (int nf = 0; nf < 8; ++nf)
#pragma unroll
        for (int r = 0; r < 4; ++r) oacc[nf][r] *= alpha[r];
    }

#pragma unroll
    for (int s2 = 0; s2 < 2; ++s2) {
      int prow = l16;
      int paddr = wv * 2048 + ((prow * 128 + s2 * 64 + lhi * 16) ^ ((prow & 7) << 4));
      bf16x8 pa = *(const bf16x8*)((char*)lP + paddr);
#pragma unroll
      for (int nf = 0; nf < 8; ++nf) {
        int rowd = nf * 16 + l16;
        int cv = (s2 * 4 + lhi) ^ (rowd & 7);
        bf16x8 vfr = *(const bf16x8*)((char*)lV + rowd * 128 + cv * 16);
        oacc[nf] = __builtin_amdgcn_mfma_f32_16x16x32_bf16(pa, vfr, oacc[nf], 0, 0, 0);
      }
    }
  }

  unsigned short* Ob = Out + ((size_t)(b * 1024) + q0 + wv * 16 + lhi * 4) * 4096 + h * 128;
#pragma unroll
  for (int r = 0; r < 4; ++r) {
    float inv = 1.f / lrow[r];
#pragma unroll
    for (int nf = 0; nf < 8; ++nf)
      Ob[(size_t)r * 4096 + nf * 16 + l16] = f2bf(oacc[nf][r] * inv);
  }
}

extern "C" void kernel_launch(void* const* d_in, const int* in_sizes, int n_in,
                              void* d_out, int out_size, void* d_ws, size_t ws_size,
                              hipStream_t stream) {
  const float* x = (const float*)d_in[0];
  const float* w_qkv = (const float*)d_in[1];
  const float* w_o = (const float*)d_in[2];
  const float* cosT = (const float*)d_in[3];
  const float* sinT = (const float*)d_in[4];

  char* ws = (char*)d_ws;
  unsigned short* wqkv_t = (unsigned short*)(ws);                 // 6144x4096 bf16
  unsigned short* wo_t   = (unsigned short*)(ws + 50331648);      // 4096x4096 bf16
  unsigned short* xb     = (unsigned short*)(ws + 83886080);      // 2048x4096 bf16
  unsigned short* Qr     = (unsigned short*)(ws + 100663296);     // 2*32*1024*128 bf16
  unsigned short* Kr     = (unsigned short*)(ws + 117440512);     // 2*8*1024*128 bf16
  unsigned short* Vt     = (unsigned short*)(ws + 121634816);     // 2*8*128*1024 bf16
  unsigned short* attn   = (unsigned short*)(ws + 125829120);     // 2048x4096 bf16

  k_prep<<<14336, 256, 0, stream>>>(x, w_qkv, xb, wqkv_t);
  k_gemm<1><<<dim3(16, 48), 256, 0, stream>>>(xb, wqkv_t, nullptr, Qr, Kr, Vt, cosT, sinT,
                                              2048, 6144, 4096);
  k_attn_wo<<<1024 + 4096, 256, 0, stream>>>(Qr, Kr, Vt, attn, w_o, wo_t);
  k_gemm<0><<<dim3(16, 32), 256, 0, stream>>>(attn, wo_t, (float*)d_out, nullptr, nullptr, nullptr,
                                              nullptr, nullptr, 2048, 4096, 4096);
}

// Round 16
// 318.826 us; speedup vs baseline: 1.0393x; 1.0033x over previous
//
#include <hip/hip_runtime.h>
#include <cstdint>
#include <cstddef>

// B=2 S=1024 H=4096 NH=32 NKV=8 HD=128 GROUPS=4
typedef short bf16x8 __attribute__((ext_vector_type(8)));
typedef float f32x4 __attribute__((ext_vector_type(4)));

__device__ __forceinline__ unsigned short f2bf(float f) {
  unsigned int u = __builtin_bit_cast(unsigned int, f);
  u += 0x7fffu + ((u >> 16) & 1u);
  return (unsigned short)(u >> 16);
}

// ---- transpose tile core: 64x64, float4 loads / bf16x8 stores; caller-provided LDS ----
__device__ __forceinline__ void transpose_tile(const float* __restrict__ src,
                                               unsigned short* __restrict__ dst,
                                               int K, int N, int n0, int k0, int tid,
                                               float* __restrict__ tb /* [64][65] */) {
#pragma unroll
  for (int i = 0; i < 4; ++i) {
    const int lr = tid >> 4, lc = (tid & 15) * 4;
    float4 v = *(const float4*)(src + (size_t)(k0 + i * 16 + lr) * N + n0 + lc);
    tb[(i * 16 + lr) * 65 + lc] = v.x;
    tb[(i * 16 + lr) * 65 + lc + 1] = v.y;
    tb[(i * 16 + lr) * 65 + lc + 2] = v.z;
    tb[(i * 16 + lr) * 65 + lc + 3] = v.w;
  }
  __syncthreads();
  const int nr = tid >> 3, kk = (tid & 7) * 8;
#pragma unroll
  for (int i = 0; i < 2; ++i) {
    int n = nr + i * 32;
    bf16x8 v;
#pragma unroll
    for (int j = 0; j < 8; ++j) v[j] = (short)f2bf(tb[(kk + j) * 65 + n]);
    *(bf16x8*)(dst + (size_t)(n0 + n) * K + k0 + kk) = v;
  }
}

// ---- prep: x convert (blocks [0,8192)) + w_qkv transpose [8192,14336) ----
__global__ __launch_bounds__(256) void k_prep(const float* __restrict__ x,
                                              const float* __restrict__ w_qkv,
                                              unsigned short* __restrict__ xb,
                                              unsigned short* __restrict__ wqkv_t) {
  __shared__ float tb[64 * 65];
  const int bid = blockIdx.x, tid = threadIdx.x;
  if (bid < 8192) {
    int i = bid * 256 + tid;
    float4 v = ((const float4*)x)[i];
    ushort4 o;
    o.x = f2bf(v.x); o.y = f2bf(v.y); o.z = f2bf(v.z); o.w = f2bf(v.w);
    ((ushort4*)xb)[i] = o;
  } else {
    int t = bid - 8192;
    transpose_tile(w_qkv, wqkv_t, 4096, 6144, (t % 96) * 64, (t / 96) * 64, tid, tb);
  }
}

// ---- GEMM (R11 proven: depth-1 reg-staged, VGPR 80): BM=BN=128, BK=64, 4 waves,
// XOR-swizzled ds_write, prefetch after barrier, T1 XCD swizzle.
// MODE 0: 2D grid, C[M,N] f32 out.
// MODE 1: 1D grid; bid<768 = qkv-proj tile (fused RoPE + Q/K/V scatter epilogue);
//         bid>=768 = one 64x64 w_o transpose tile, co-scheduled into the idle
//         LDS/wave/BW slots of the GEMM's 3-blocks/CU steady state (LDS overlaid
//         in the same 32KB footprint so GEMM occupancy is untouched).
template <int MODE>
__global__ __launch_bounds__(256) void k_gemm(const unsigned short* __restrict__ A,
                                              const unsigned short* __restrict__ Bt,
                                              float* __restrict__ C,
                                              unsigned short* __restrict__ Qr,
                                              unsigned short* __restrict__ Kr,
                                              unsigned short* __restrict__ Vt,
                                              const float* __restrict__ cosT,
                                              const float* __restrict__ sinT,
                                              const float* __restrict__ w_o,
                                              unsigned short* __restrict__ wo_t,
                                              int M, int N, int K) {
  __shared__ __align__(16) char smem[32768]; // GEMM: lA|lB ; transpose: 64x65 f32
  unsigned short* lA = (unsigned short*)smem;
  unsigned short* lB = (unsigned short*)(smem + 16384);
  const int tid = threadIdx.x;

  int bm, bn;
  if (MODE == 1) {
    const int bid = blockIdx.x;
    if (bid >= 768) { // w_o transpose backfill
      int t = bid - 768;
      transpose_tile(w_o, wo_t, 4096, 4096, (t & 63) * 64, (t >> 6) * 64, tid, (float*)smem);
      return;
    }
    const int swz = (bid & 7) * 96 + (bid >> 3); // T1: 768 tiles, 16 bm x 48 bn
    bm = (swz & 15) * 128;
    bn = (swz >> 4) * 128;
  } else {
    const int lid = blockIdx.y * gridDim.x + blockIdx.x;
    const int cpx = (gridDim.x * gridDim.y) >> 3;
    const int swz = (lid & 7) * cpx + (lid >> 3);
    bm = (swz % gridDim.x) * 128;
    bn = (swz / gridDim.x) * 128;
  }

  const int lane = tid & 63, wv = tid >> 6;
  const int wr = wv >> 1, wc = wv & 1;
  const int l16 = lane & 15, lhi = lane >> 4;
  f32x4 acc[4][4] = {};
  bf16x8 ar[4], br[4];

#pragma unroll
  for (int i = 0; i < 4; ++i) {
    int c = tid + i * 256, row = c >> 3, c16 = c & 7;
    ar[i] = *(const bf16x8*)(A + (size_t)(bm + row) * K + 0 + c16 * 8);
    br[i] = *(const bf16x8*)(Bt + (size_t)(bn + row) * K + 0 + c16 * 8);
  }
  const int nkt = K >> 6;
  for (int kt = 0; kt < nkt; ++kt) {
    __syncthreads();
#pragma unroll
    for (int i = 0; i < 4; ++i) {
      int c = tid + i * 256, row = c >> 3, c16 = c & 7;
      int pc = c16 ^ (row & 7);
      *(bf16x8*)((char*)lA + row * 128 + pc * 16) = ar[i];
      *(bf16x8*)((char*)lB + row * 128 + pc * 16) = br[i];
    }
    __syncthreads();
    if (kt + 1 < nkt) {
      int kofs = (kt + 1) << 6;
#pragma unroll
      for (int i = 0; i < 4; ++i) {
        int c = tid + i * 256, row = c >> 3, c16 = c & 7;
        ar[i] = *(const bf16x8*)(A + (size_t)(bm + row) * K + kofs + c16 * 8);
        br[i] = *(const bf16x8*)(Bt + (size_t)(bn + row) * K + kofs + c16 * 8);
      }
    }
#pragma unroll
    for (int s = 0; s < 2; ++s) {
      bf16x8 af[4], bfr[4];
#pragma unroll
      for (int f = 0; f < 4; ++f) {
        int rowa = wr * 64 + f * 16 + l16;
        int ca = (s * 4 + lhi) ^ (rowa & 7);
        af[f] = *(const bf16x8*)((char*)lA + rowa * 128 + ca * 16);
        int rowb = wc * 64 + f * 16 + l16;
        int cb = (s * 4 + lhi) ^ (rowb & 7);
        bfr[f] = *(const bf16x8*)((char*)lB + rowb * 128 + cb * 16);
      }
#pragma unroll
      for (int fi = 0; fi < 4; ++fi)
#pragma unroll
        for (int fj = 0; fj < 4; ++fj)
          acc[fi][fj] = __builtin_amdgcn_mfma_f32_16x16x32_bf16(af[fi], bfr[fj], acc[fi][fj], 0, 0, 0);
    }
  }

  if (MODE == 0) {
#pragma unroll
    for (int fi = 0; fi < 4; ++fi) {
      int rbase = bm + wr * 64 + fi * 16 + lhi * 4;
#pragma unroll
      for (int fj = 0; fj < 4; ++fj) {
        int col = bn + wc * 64 + fj * 16 + l16;
#pragma unroll
        for (int r = 0; r < 4; ++r)
          C[(size_t)(rbase + r) * N + col] = acc[fi][fj][r];
      }
    }
  } else {
    // qkv: cols [0,4096)=Q rope, [4096,5120)=K rope, [5120,6144)=V transpose.
#pragma unroll
    for (int fi = 0; fi < 4; ++fi) {
      int rbase = bm + wr * 64 + fi * 16 + lhi * 4;
      int b = rbase >> 10, sbase = rbase & 1023;
#pragma unroll
      for (int fj = 0; fj < 4; ++fj) {
        int col = bn + wc * 64 + fj * 16 + l16;
        if (col < 5120) {
          int i = (col & 127) >> 1;
          float sgn = (col & 1) ? 1.0f : -1.0f;
          unsigned short* dst;
          if (col < 4096)
            dst = Qr + ((size_t)(b * 32 + (col >> 7)) * 1024) * 128 + (col & 127);
          else
            dst = Kr + ((size_t)(b * 8 + ((col - 4096) >> 7)) * 1024) * 128 + (col & 127);
#pragma unroll
          for (int r = 0; r < 4; ++r) {
            float own = acc[fi][fj][r];
            float other = __shfl_xor(own, 1);
            int s = sbase + r;
            float c = cosT[s * 64 + i], sn = sinT[s * 64 + i];
            dst[(size_t)s * 128] = f2bf(own * c + sgn * other * sn);
          }
        } else {
          int kvh = (col - 5120) >> 7, d = col & 127;
          unsigned short* dst = Vt + ((size_t)(b * 8 + kvh) * 128 + d) * 1024;
#pragma unroll
          for (int r = 0; r < 4; ++r) dst[sbase + r] = f2bf(acc[fi][fj][r]);
        }
      }
    }
  }
}

// ---- flash attention (R13 proven): QBLK=64, 4 waves, LPT qt order, T13 defer-max,
// T14 post-barrier prefetch, XOR-swizzled K/V LDS ----
__global__ __launch_bounds__(256) void k_attn(const unsigned short* __restrict__ Qr,
                                              const unsigned short* __restrict__ Kr,
                                              const unsigned short* __restrict__ Vt,
                                              unsigned short* __restrict__ Out) {
  __shared__ __align__(16) unsigned short lK[64 * 128];
  __shared__ __align__(16) unsigned short lV[128 * 64];
  __shared__ __align__(16) unsigned short lP[4 * 16 * 64];
  const int tid = threadIdx.x, lane = tid & 63, wv = tid >> 6;
  const int qt = (int)gridDim.x - 1 - (int)blockIdx.x; // LPT: heavy blocks first
  const int h = blockIdx.y, b = blockIdx.z;
  const int kvh = h >> 2;
  const int q0 = qt * 64;
  const int l16 = lane & 15, lhi = lane >> 4;

  const unsigned short* Qbase = Qr + ((size_t)(b * 32 + h) * 1024 + q0 + wv * 16 + l16) * 128;
  bf16x8 qf[4];
#pragma unroll
  for (int s = 0; s < 4; ++s) qf[s] = *(const bf16x8*)(Qbase + s * 32 + lhi * 8);

  const unsigned short* Kbase = Kr + (size_t)(b * 8 + kvh) * 1024 * 128;
  const unsigned short* Vbase = Vt + (size_t)(b * 8 + kvh) * 128 * 1024;

  f32x4 oacc[8] = {};
  float mrow[4] = {-1e30f, -1e30f, -1e30f, -1e30f};
  float lrow[4] = {0.f, 0.f, 0.f, 0.f};
  const int ntk = qt + 1;
  bf16x8 kreg[4], vreg[4];

#pragma unroll
  for (int i = 0; i < 4; ++i) {
    int c = tid + i * 256;
    int krow = c >> 4, kc = c & 15;
    kreg[i] = *(const bf16x8*)(Kbase + (size_t)krow * 128 + kc * 8);
    int vrow = c >> 3, vc = c & 7;
    vreg[i] = *(const bf16x8*)(Vbase + (size_t)vrow * 1024 + vc * 8);
  }

  for (int kt = 0; kt < ntk; ++kt) {
    const int k0 = kt * 64;
    __syncthreads();
#pragma unroll
    for (int i = 0; i < 4; ++i) {
      int c = tid + i * 256;
      int krow = c >> 4, kc = c & 15;
      *(bf16x8*)((char*)lK + krow * 256 + (kc ^ (krow & 7)) * 16) = kreg[i];
      int vrow = c >> 3, vc = c & 7;
      *(bf16x8*)((char*)lV + vrow * 128 + (vc ^ (vrow & 7)) * 16) = vreg[i];
    }
    __syncthreads();

    if (kt + 1 < ntk) {
      const int kn = (kt + 1) * 64;
#pragma unroll
      for (int i = 0; i < 4; ++i) {
        int c = tid + i * 256;
        int krow = c >> 4, kc = c & 15;
        kreg[i] = *(const bf16x8*)(Kbase + (size_t)(kn + krow) * 128 + kc * 8);
        int vrow = c >> 3, vc = c & 7;
        vreg[i] = *(const bf16x8*)(Vbase + (size_t)vrow * 1024 + kn + vc * 8);
      }
    }

    f32x4 sacc[4] = {};
#pragma unroll
    for (int kf = 0; kf < 4; ++kf) {
      int rowk = kf * 16 + l16;
#pragma unroll
      for (int s = 0; s < 4; ++s) {
        int ck = (s * 4 + lhi) ^ (rowk & 7);
        bf16x8 kfr = *(const bf16x8*)((char*)lK + rowk * 256 + ck * 16);
        sacc[kf] = __builtin_amdgcn_mfma_f32_16x16x32_bf16(qf[s], kfr, sacc[kf], 0, 0, 0);
      }
    }

    const int qg = q0 + wv * 16 + lhi * 4;
    float mt[4] = {-1e30f, -1e30f, -1e30f, -1e30f};
#pragma unroll
    for (int kf = 0; kf < 4; ++kf) {
      int kg = k0 + kf * 16 + l16;
#pragma unroll
      for (int r = 0; r < 4; ++r) {
        float v = sacc[kf][r] * 0.08838834764831845f;
        v = (kg <= qg + r) ? v : -1e9f;
        sacc[kf][r] = v;
        mt[r] = fmaxf(mt[r], v);
      }
    }
#pragma unroll
    for (int r = 0; r < 4; ++r) {
#pragma unroll
      for (int off = 1; off < 16; off <<= 1) mt[r] = fmaxf(mt[r], __shfl_xor(mt[r], off));
    }

    bool need = false;
#pragma unroll
    for (int r = 0; r < 4; ++r) need = need || (mt[r] > mrow[r] + 8.0f);
    const bool doresc = (__ballot(need) != 0ull);

    float alpha[4], rs[4];
#pragma unroll
    for (int r = 0; r < 4; ++r) {
      if (doresc) {
        float mn = fmaxf(mrow[r], mt[r]);
        alpha[r] = __expf(mrow[r] - mn);
        mrow[r] = mn;
      } else {
        alpha[r] = 1.0f;
      }
      rs[r] = 0.f;
    }
#pragma unroll
    for (int kf = 0; kf < 4; ++kf) {
      int key = kf * 16 + l16;
#pragma unroll
      for (int r = 0; r < 4; ++r) {
        float p = __expf(sacc[kf][r] - mrow[r]);
        rs[r] += p;
        int prow = lhi * 4 + r;
        int addr = wv * 2048 + ((prow * 128 + key * 2) ^ ((prow & 7) << 4));
        *(unsigned short*)((char*)lP + addr) = f2bf(p);
      }
    }
#pragma unroll
    for (int r = 0; r < 4; ++r) {
#pragma unroll
      for (int off = 1; off < 16; off <<= 1) rs[r] += __shfl_xor(rs[r], off);
      lrow[r] = lrow[r] * alpha[r] + rs[r];
    }
    if (doresc) {
#pragma unroll
      for (int nf = 0; nf < 8; ++nf)
#pragma unroll
        for (int r = 0; r < 4; ++r) oacc[nf][r] *= alpha[r];
    }

#pragma unroll
    for (int s2 = 0; s2 < 2; ++s2) {
      int prow = l16;
      int paddr = wv * 2048 + ((prow * 128 + s2 * 64 + lhi * 16) ^ ((prow & 7) << 4));
      bf16x8 pa = *(const bf16x8*)((char*)lP + paddr);
#pragma unroll
      for (int nf = 0; nf < 8; ++nf) {
        int rowd = nf * 16 + l16;
        int cv = (s2 * 4 + lhi) ^ (rowd & 7);
        bf16x8 vfr = *(const bf16x8*)((char*)lV + rowd * 128 + cv * 16);
        oacc[nf] = __builtin_amdgcn_mfma_f32_16x16x32_bf16(pa, vfr, oacc[nf], 0, 0, 0);
      }
    }
  }

  unsigned short* Ob = Out + ((size_t)(b * 1024) + q0 + wv * 16 + lhi * 4) * 4096 + h * 128;
#pragma unroll
  for (int r = 0; r < 4; ++r) {
    float inv = 1.f / lrow[r];
#pragma unroll
    for (int nf = 0; nf < 8; ++nf)
      Ob[(size_t)r * 4096 + nf * 16 + l16] = f2bf(oacc[nf][r] * inv);
  }
}

extern "C" void kernel_launch(void* const* d_in, const int* in_sizes, int n_in,
                              void* d_out, int out_size, void* d_ws, size_t ws_size,
                              hipStream_t stream) {
  const float* x = (const float*)d_in[0];
  const float* w_qkv = (const float*)d_in[1];
  const float* w_o = (const float*)d_in[2];
  const float* cosT = (const float*)d_in[3];
  const float* sinT = (const float*)d_in[4];

  char* ws = (char*)d_ws;
  unsigned short* wqkv_t = (unsigned short*)(ws);                 // 6144x4096 bf16
  unsigned short* wo_t   = (unsigned short*)(ws + 50331648);      // 4096x4096 bf16
  unsigned short* xb     = (unsigned short*)(ws + 83886080);      // 2048x4096 bf16
  unsigned short* Qr     = (unsigned short*)(ws + 100663296);     // 2*32*1024*128 bf16
  unsigned short* Kr     = (unsigned short*)(ws + 117440512);     // 2*8*1024*128 bf16
  unsigned short* Vt     = (unsigned short*)(ws + 121634816);     // 2*8*128*1024 bf16
  unsigned short* attn   = (unsigned short*)(ws + 125829120);     // 2048x4096 bf16

  k_prep<<<14336, 256, 0, stream>>>(x, w_qkv, xb, wqkv_t);
  k_gemm<1><<<768 + 4096, 256, 0, stream>>>(xb, wqkv_t, nullptr, Qr, Kr, Vt, cosT, sinT,
                                            w_o, wo_t, 2048, 6144, 4096);
  k_attn<<<dim3(16, 32, 2), 256, 0, stream>>>(Qr, Kr, Vt, attn);
  k_gemm<0><<<dim3(16, 32), 256, 0, stream>>>(attn, wo_t, (float*)d_out, nullptr, nullptr, nullptr,
                                              nullptr, nullptr, nullptr, nullptr, 2048, 4096, 4096);
}